// Round 22
// baseline (120.849 us; speedup 1.0000x reference)
//
#include <hip/hip_runtime.h>
#include <stdint.h>

#define SEQ 4096
#define DM 768
#define NH 12
#define HD 64

typedef __attribute__((ext_vector_type(8))) short bf8;
typedef __attribute__((ext_vector_type(4))) float f4;
typedef __attribute__((ext_vector_type(16))) float f32x16;

static __device__ __forceinline__ f4 mfma_bf16(bf8 a, bf8 b, f4 c) {
  return __builtin_amdgcn_mfma_f32_16x16x32_bf16(a, b, c, 0, 0, 0);
}
static __device__ __forceinline__ f32x16 mfma32(bf8 a, bf8 b, f32x16 c) {
  return __builtin_amdgcn_mfma_f32_32x32x16_bf16(a, b, c, 0, 0, 0);
}

// RNE float->bf16 (bit pattern)
static __device__ __forceinline__ unsigned short f2bf(float f) {
  unsigned int u = __float_as_uint(f);
  u += 0x7FFFu + ((u >> 16) & 1u);
  return (unsigned short)(u >> 16);
}

// packed f32 pair -> bf16 pair (lo in low 16, hi in high 16)
static __device__ __forceinline__ unsigned int cvtpk(float lo, float hi) {
  unsigned int r;
  asm("v_cvt_pk_bf16_f32 %0, %1, %2" : "=v"(r) : "v"(lo), "v"(hi));
  return r;
}

static __device__ __forceinline__ void gload_lds16(const void* g, void* l) {
  __builtin_amdgcn_global_load_lds(
      (const __attribute__((address_space(1))) void*)g,
      (__attribute__((address_space(3))) void*)l, 16, 0, 0);
}

// ---- fused prologue: transpose-cast W (blocks 0..2303) + cast x (rest) ----
__global__ __launch_bounds__(256) void k_pro(const float* __restrict__ x,
                                             const float* __restrict__ w0,
                                             const float* __restrict__ w1,
                                             const float* __restrict__ w2,
                                             const float* __restrict__ w3,
                                             unsigned short* __restrict__ xb,
                                             unsigned short* __restrict__ wt) {
  const int id = (int)blockIdx.x;
  if (id < 2304) {
    const int z = id / 576, rem = id % 576;
    const int by = rem / 24, bx = rem % 24;
    const float* W = z == 0 ? w0 : z == 1 ? w1 : z == 2 ? w2 : w3;
    unsigned short* WT = wt + (size_t)z * DM * DM;
    __shared__ float t[32][33];
    int c0 = bx * 32, r0 = by * 32;
    int lx = threadIdx.x & 31, ly = threadIdx.x >> 5;
#pragma unroll
    for (int rr = 0; rr < 32; rr += 8)
      t[ly + rr][lx] = W[(size_t)(r0 + ly + rr) * DM + c0 + lx];
    __syncthreads();
#pragma unroll
    for (int rr = 0; rr < 32; rr += 8)
      WT[(size_t)(c0 + ly + rr) * DM + r0 + lx] = f2bf(t[lx][ly + rr]);
  } else {
    int i = ((id - 2304) * 256 + threadIdx.x) * 4;
    float4 v = *reinterpret_cast<const float4*>(x + i);
    ushort4 o;
    o.x = f2bf(v.x); o.y = f2bf(v.y); o.z = f2bf(v.z); o.w = f2bf(v.w);
    *reinterpret_cast<ushort4*>(xb + i) = o;
  }
}

// ---- bf16 MFMA GEMM, 128x128 tile, 4 waves (2x2), wave tile 64x64 --------
// Single-buffered (R16-proven). 1D grid with XCD-chunked swizzle (T1).
// MODE 3: fused QKV. MODE 2: out-proj.
template <int MODE, int NY>
__global__ __launch_bounds__(256) void k_gemm2(const unsigned short* __restrict__ A,
                                               const unsigned short* __restrict__ Bt,
                                               unsigned short* __restrict__ Qh,
                                               unsigned short* __restrict__ Kh,
                                               unsigned short* __restrict__ Vtl,
                                               float* __restrict__ Cf,
                                               const float* __restrict__ bias,
                                               float qscale) {
  __shared__ unsigned short sA[128 * 32];
  __shared__ unsigned short sB[128 * 32];
  const int t = threadIdx.x, lane = t & 63, w = t >> 6;
  const int wr = w >> 1, wc = w & 1;
  const int c = lane & 15, g = lane >> 4;
  constexpr int NWG = 32 * NY;
  const int L = (int)blockIdx.x;
  const int W = (L & 7) * (NWG / 8) + (L >> 3);
  const int brow = (W / NY) * 128, bcol = (W % NY) * 128;
  f4 acc[4][4] = {};
  for (int k0 = 0; k0 < DM; k0 += 32) {
#pragma unroll
    for (int i = 0; i < 2; ++i) {
      int slot = w * 2 + i;
      int chunk = slot * 64 + lane;
      int row = chunk >> 2;
      int sl = (chunk & 3) ^ ((row >> 1) & 3);
      gload_lds16(A + (size_t)(brow + row) * DM + k0 + sl * 8, &sA[slot * 512]);
    }
#pragma unroll
    for (int i = 0; i < 2; ++i) {
      int slot = w * 2 + i;
      int chunk = slot * 64 + lane;
      int row = chunk >> 2;
      int sl = (chunk & 3) ^ ((row >> 1) & 3);
      gload_lds16(Bt + (size_t)(bcol + row) * DM + k0 + sl * 8, &sB[slot * 512]);
    }
    __syncthreads();
    bf8 af[4], bfr[4];
#pragma unroll
    for (int m = 0; m < 4; ++m) {
      int row = wr * 64 + m * 16 + c;
      int off = row * 64 + ((g * 16) ^ (((row >> 1) & 3) << 4));
      af[m] = *reinterpret_cast<const bf8*>(reinterpret_cast<const char*>(sA) + off);
    }
#pragma unroll
    for (int n = 0; n < 4; ++n) {
      int row = wc * 64 + n * 16 + c;
      int off = row * 64 + ((g * 16) ^ (((row >> 1) & 3) << 4));
      bfr[n] = *reinterpret_cast<const bf8*>(reinterpret_cast<const char*>(sB) + off);
    }
#pragma unroll
    for (int m = 0; m < 4; ++m)
#pragma unroll
      for (int n = 0; n < 4; ++n)
        acc[m][n] = mfma_bf16(af[m], bfr[n], acc[m][n]);
    __syncthreads();
  }
#pragma unroll
  for (int m = 0; m < 4; ++m) {
#pragma unroll
    for (int n = 0; n < 4; ++n) {
      int col = bcol + wc * 64 + n * 16 + c;
      int row0 = brow + wr * 64 + m * 16 + g * 4;
      if (MODE == 3) {
        int zone = col / 768;
        int ci = col - zone * 768;
        int h = ci >> 6, d = ci & 63;
        if (zone == 0) {
#pragma unroll
          for (int r = 0; r < 4; ++r)
            Qh[((size_t)h * SEQ + row0 + r) * 64 + d] = f2bf(acc[m][n][r] * qscale);
        } else if (zone == 1) {
#pragma unroll
          for (int r = 0; r < 4; ++r)
            Kh[((size_t)h * SEQ + row0 + r) * 64 + d] = f2bf(acc[m][n][r]);
        } else {
          ushort4 p;
          p.x = f2bf(acc[m][n][0]); p.y = f2bf(acc[m][n][1]);
          p.z = f2bf(acc[m][n][2]); p.w = f2bf(acc[m][n][3]);
          // row0 = k index; tile = row0>>5, ks = row0&31 (row0%4==0 -> in-tile)
          *reinterpret_cast<ushort4*>(
              Vtl + ((((size_t)h * 128 + (row0 >> 5)) * 64 + d) * 32 + (row0 & 31))) = p;
        }
      } else {
#pragma unroll
        for (int r = 0; r < 4; ++r)
          Cf[(size_t)(row0 + r) * DM + col] = acc[m][n][r] + bias[col];
      }
    }
  }
}

// ---- attention helpers ----------------------------------------------------
#define PSWAP(a, b) asm volatile("v_permlane32_swap_b32 %0, %1" : "+v"(a), "+v"(b))
#define SGB() __builtin_amdgcn_sched_barrier(0)

// Stage a 32x64 bf16 K tile (contiguous 4KB, 128-B rows) into LDS.
// Source pre-swizzled (chunk ^= row&7) to match the swizzled ds_read.
#define STAGE4K(srcbase, tile, dst) do {                                      \
    const unsigned short* s_ = (srcbase) + (size_t)(tile) * 2048 + kLaneOffK; \
    _Pragma("unroll")                                                         \
    for (int j_ = 0; j_ < 4; ++j_)                                            \
      gload_lds16(s_ + j_ * 512, (dst) + j_ * 1024);                          \
  } while (0)

// Stage a 64x32 bf16 V tile (contiguous 4KB, 64-B rows). Source pre-swizzled:
// chunk ^= (row&3)^((row>>2)&3)^((row>>4)&3); row = 16j + (lane>>2).
#define STAGE4KV(srcbase, tile, dst) do {                                     \
    const unsigned short* s_ = (srcbase) + (size_t)(tile) * 2048;             \
    _Pragma("unroll")                                                         \
    for (int j_ = 0; j_ < 4; ++j_) {                                          \
      int c_ = (lane & 3) ^ ((lane >> 2) & 3) ^ ((lane >> 4) & 3) ^ j_;       \
      gload_lds16(s_ + j_ * 512 + (lane >> 2) * 32 + c_ * 8,                  \
                  (dst) + j_ * 1024);                                         \
    }                                                                         \
  } while (0)

// 16 P-values (one f32x16, already masked) -> exp -> two bf8 B-fragments.
// Accumulates P-sum into ls_.
#define PBUILD(sv, mn_, ls_, pfx, pfy) do {                                   \
    float p0_ = __builtin_amdgcn_exp2f(sv[0] - mn_);                          \
    float p1_ = __builtin_amdgcn_exp2f(sv[1] - mn_);                          \
    float p2_ = __builtin_amdgcn_exp2f(sv[2] - mn_);                          \
    float p3_ = __builtin_amdgcn_exp2f(sv[3] - mn_);                          \
    float p4_ = __builtin_amdgcn_exp2f(sv[4] - mn_);                          \
    float p5_ = __builtin_amdgcn_exp2f(sv[5] - mn_);                          \
    float p6_ = __builtin_amdgcn_exp2f(sv[6] - mn_);                          \
    float p7_ = __builtin_amdgcn_exp2f(sv[7] - mn_);                          \
    unsigned int wa0_ = cvtpk(p0_, p1_), wa1_ = cvtpk(p2_, p3_);              \
    unsigned int wb0_ = cvtpk(p4_, p5_), wb1_ = cvtpk(p6_, p7_);              \
    ls_ += ((p0_ + p1_) + (p2_ + p3_)) + ((p4_ + p5_) + (p6_ + p7_));         \
    float q0_ = __builtin_amdgcn_exp2f(sv[8] - mn_);                          \
    float q1_ = __builtin_amdgcn_exp2f(sv[9] - mn_);                          \
    float q2_ = __builtin_amdgcn_exp2f(sv[10] - mn_);                         \
    float q3_ = __builtin_amdgcn_exp2f(sv[11] - mn_);                         \
    float q4_ = __builtin_amdgcn_exp2f(sv[12] - mn_);                         \
    float q5_ = __builtin_amdgcn_exp2f(sv[13] - mn_);                         \
    float q6_ = __builtin_amdgcn_exp2f(sv[14] - mn_);                         \
    float q7_ = __builtin_amdgcn_exp2f(sv[15] - mn_);                         \
    unsigned int wc0_ = cvtpk(q0_, q1_), wc1_ = cvtpk(q2_, q3_);              \
    unsigned int wd0_ = cvtpk(q4_, q5_), wd1_ = cvtpk(q6_, q7_);              \
    ls_ += ((q0_ + q1_) + (q2_ + q3_)) + ((q4_ + q5_) + (q6_ + q7_));         \
    PSWAP(wa0_, wb0_);                                                        \
    PSWAP(wa1_, wb1_);                                                        \
    PSWAP(wc0_, wd0_);                                                        \
    PSWAP(wc1_, wd1_);                                                        \
    uint4 u0_ = {wa0_, wa1_, wb0_, wb1_};                                     \
    uint4 u1_ = {wc0_, wc1_, wd0_, wd1_};                                     \
    pfx = *reinterpret_cast<bf8*>(&u0_);                                      \
    pfy = *reinterpret_cast<bf8*>(&u1_);                                      \
  } while (0)

#define FMAX8(v, i0) fmaxf(fmaxf(fmaxf(v[i0], v[i0+1]), fmaxf(v[i0+2], v[i0+3])), \
                           fmaxf(fmaxf(v[i0+4], v[i0+5]), fmaxf(v[i0+6], v[i0+7])))

// Cross-half (lane i <-> i+32) reduce via permlane32_swap. The opaque asm
// copy forces 'cp' into a register DISTINCT from 'x' (R7 lesson).
#define XHALF_MAX(x) do {                                                     \
    float cp_ = (x);                                                          \
    asm volatile("" : "+v"(cp_));                                             \
    PSWAP((x), cp_);                                                          \
    (x) = fmaxf((x), cp_);                                                    \
  } while (0)
#define XHALF_ADD(x) do {                                                     \
    float cp_ = (x);                                                          \
    asm volatile("" : "+v"(cp_));                                             \
    PSWAP((x), cp_);                                                          \
    (x) = (x) + cp_;                                                          \
  } while (0)

// Softmax for one q-tile's 32-k scores (mask, running max w/ defer-max T13,
// P-build, l update). Produces pf0/pf1. Identical math to R19's step body.
#define SOFTMAX32(sv, t, dtv, qgv, mv, lv, ov0, ov1, pf0, pf1) do {           \
    if ((t) == (dtv)) {                                                       \
      _Pragma("unroll")                                                       \
      for (int r_ = 0; r_ < 16; ++r_) {                                       \
        int kr_ = (t) * 32 + (r_ & 3) + 8 * (r_ >> 2) + 4 * hi;               \
        sv[r_] = (kr_ > (qgv)) ? -1e30f : sv[r_];                             \
      }                                                                       \
    }                                                                         \
    float tm_ = fmaxf(FMAX8(sv, 0), FMAX8(sv, 8));                            \
    XHALF_MAX(tm_);                                                           \
    float mn_, al_;                                                           \
    if (__all(tm_ <= (mv) + 8.f)) {                                           \
      mn_ = (mv);                                                             \
      al_ = 1.0f;                                                             \
    } else {                                                                  \
      mn_ = fmaxf((mv), tm_);                                                 \
      al_ = __builtin_amdgcn_exp2f((mv) - mn_);                               \
      (mv) = mn_;                                                             \
      _Pragma("unroll")                                                       \
      for (int r_ = 0; r_ < 16; ++r_) { ov0[r_] *= al_; ov1[r_] *= al_; }     \
    }                                                                         \
    float ls_ = 0.f;                                                          \
    PBUILD(sv, mn_, ls_, pf0, pf1);                                           \
    XHALF_ADD(ls_);                                                           \
    (lv) = (lv) * al_ + ls_;                                                  \
  } while (0)

// Merge+store one q-tile's split-K result (proven R19 epilogue body).
#define MERGE_STORE(qtv, mv, lv, ov0, ov1) do {                               \
    _Pragma("unroll")                                                         \
    for (int r_ = 0; r_ < 16; ++r_) {                                         \
      int dr_ = (r_ & 3) + 8 * (r_ >> 2) + 4 * hi;                            \
      sO[w * 2048 + dr_ * 32 + ql] = ov0[r_];                                 \
      sO[w * 2048 + (32 + dr_) * 32 + ql] = ov1[r_];                          \
    }                                                                         \
    if (hi == 0) { sM[w * 32 + ql] = (mv); sL[w * 32 + ql] = (lv); }          \
    __syncthreads();                                                          \
    {                                                                         \
      const int q_ = tid & 31;                                                \
      const int dblk_ = tid >> 5;                                             \
      float m0_ = sM[q_], m1_ = sM[32 + q_], m2_ = sM[64 + q_],               \
            m3_ = sM[96 + q_];                                                \
      float mn_ = fmaxf(fmaxf(m0_, m1_), fmaxf(m2_, m3_));                    \
      float a0_ = __builtin_amdgcn_exp2f(m0_ - mn_);                          \
      float a1_ = __builtin_amdgcn_exp2f(m1_ - mn_);                          \
      float a2_ = __builtin_amdgcn_exp2f(m2_ - mn_);                          \
      float a3_ = __builtin_amdgcn_exp2f(m3_ - mn_);                          \
      float inv_ = 1.f / (a0_ * sL[q_] + a1_ * sL[32 + q_] +                  \
                          a2_ * sL[64 + q_] + a3_ * sL[96 + q_]);             \
      a0_ *= inv_; a1_ *= inv_; a2_ *= inv_; a3_ *= inv_;                     \
      unsigned short* cp_ = ctx + (size_t)((qtv) * 32 + q_) * DM + h * HD +   \
                            dblk_ * 8;                                        \
      _Pragma("unroll")                                                       \
      for (int j_ = 0; j_ < 8; j_ += 2) {                                     \
        int d_ = dblk_ * 8 + j_;                                              \
        float v0_ = sO[d_ * 32 + q_] * a0_ + sO[2048 + d_ * 32 + q_] * a1_ +  \
                    sO[4096 + d_ * 32 + q_] * a2_ + sO[6144 + d_ * 32 + q_] * a3_; \
        float v1_ = sO[(d_ + 1) * 32 + q_] * a0_ +                            \
                    sO[2048 + (d_ + 1) * 32 + q_] * a1_ +                     \
                    sO[4096 + (d_ + 1) * 32 + q_] * a2_ +                     \
                    sO[6144 + (d_ + 1) * 32 + q_] * a3_;                      \
        *reinterpret_cast<unsigned int*>(cp_ + j_) = cvtpk(v0_, v1_);         \
      }                                                                       \
    }                                                                         \
  } while (0)

// ---- causal flash attention: ONE-PASS paired q-tiles (R22) ---------------
// qtA=b, qtB=127-b share the head's K/V; A's k-range is a prefix of B's.
// One loop over B's k-tiles: K/V staged ONCE, fragments shared by both
// q-tiles (same fences/reads, 2x MFMA+softmax on the shared prefix).
// Split-K x4 + XCD chunking as before; two sequential merges at the end.
// (256,3): 170-VGPR cap absorbs the dual-state live peak without spills;
// 768 blocks = exactly 3/CU.
__global__ __launch_bounds__(256, 3) void k_attn(const unsigned short* __restrict__ Qh,
                                                 const unsigned short* __restrict__ Kh,
                                                 const unsigned short* __restrict__ Vt,
                                                 unsigned short* __restrict__ ctx) {
  const int tid = threadIdx.x;
  const int lane = tid & 63;
  const int w = tid >> 6;  // split-K wave index, 0..3
  const int ql = lane & 31, hi = lane >> 5;
  const int xq = ql & 7;
  const int prA = (ql & 3) ^ ((ql >> 2) & 3) ^ ((ql >> 4) & 3);
  const int prB = prA ^ 2;

  const int L = (int)blockIdx.x;          // 0..767
  const int W = (L & 7) * 96 + (L >> 3);  // XCD-chunked work id
  const int h = W >> 6;
  const int b = W & 63;

  __shared__ __align__(16) char smem[33792];
  char* kbuf = smem + w * 4096;           // [0,16K)
  char* vbuf = smem + 16384 + w * 4096;   // [16K,32K)
  float* sO = (float*)smem;               // [4][64][32] overlays staging
  float* sM = (float*)(smem + 32768);     // [4][32]
  float* sL = (float*)(smem + 33280);     // [4][32]

  const unsigned short* Khp = Kh + (size_t)h * SEQ * 64;
  const unsigned short* Qhp = Qh + (size_t)h * SEQ * 64;
  const unsigned short* Vtp = Vt + (size_t)h * SEQ * 64;  // tiled [128][64][32]
  // K staging source offset (shorts): row = lane>>3, chunk^row (128-B rows)
  const int kLaneOffK = (lane >> 3) * 64 + ((lane & 7) ^ (lane >> 3)) * 8;

  const int qtA = b, qtB = 127 - b;
  const int qgA = qtA * 32 + ql, qgB = qtB * 32 + ql;
  const int dtA = qtA, dtB = qtB;

  bf8 qfA[4], qfB[4];
  {
    const unsigned short* qp = Qhp + (size_t)qgA * 64 + hi * 8;
    qfA[0] = *reinterpret_cast<const bf8*>(qp);
    qfA[1] = *reinterpret_cast<const bf8*>(qp + 16);
    qfA[2] = *reinterpret_cast<const bf8*>(qp + 32);
    qfA[3] = *reinterpret_cast<const bf8*>(qp + 48);
    const unsigned short* qpB = Qhp + (size_t)qgB * 64 + hi * 8;
    qfB[0] = *reinterpret_cast<const bf8*>(qpB);
    qfB[1] = *reinterpret_cast<const bf8*>(qpB + 16);
    qfB[2] = *reinterpret_cast<const bf8*>(qpB + 32);
    qfB[3] = *reinterpret_cast<const bf8*>(qpB + 48);
  }
  f32x16 o0A = {}, o1A = {}, o0B = {}, o1B = {};
  float mA = -1e30f, lA = 0.f, mB = -1e30f, lB = 0.f;

  const int ntA = (dtA >= w) ? ((dtA - w) >> 2) + 1 : 0;
  const int ntB = ((dtB - w) >> 2) + 1;  // dtB >= 64 > w always

  STAGE4K(Khp, w, kbuf);
  STAGE4KV(Vtp, w, vbuf);
  for (int i = 0; i < ntB; ++i) {
    const int t = w + 4 * i;
    const int doA = (i < ntA);          // wave-uniform
    const int stage_ = (i + 1 < ntB);   // wave-uniform

    asm volatile("s_waitcnt vmcnt(0)" ::: "memory");
    SGB();
    const char* kr0_ = kbuf + ql * 128;
    bf8 ka0_ = *(const bf8*)(kr0_ + (((hi) ^ xq) << 4));
    bf8 ka1_ = *(const bf8*)(kr0_ + (((2 + hi) ^ xq) << 4));
    bf8 ka2_ = *(const bf8*)(kr0_ + (((4 + hi) ^ xq) << 4));
    bf8 ka3_ = *(const bf8*)(kr0_ + (((6 + hi) ^ xq) << 4));
    SGB();
    asm volatile("s_waitcnt lgkmcnt(0)" ::: "memory");
    SGB();
    if (stage_) STAGE4K(Khp, t + 4, kbuf);

    // QK for both tiles (shared K-frags; independent chains)
    f32x16 sB_ = {};
    __builtin_amdgcn_s_setprio(1);
    sB_ = mfma32(ka0_, qfB[0], sB_);
    sB_ = mfma32(ka1_, qfB[1], sB_);
    sB_ = mfma32(ka2_, qfB[2], sB_);
    sB_ = mfma32(ka3_, qfB[3], sB_);
    __builtin_amdgcn_s_setprio(0);
    f32x16 sA_ = {};
    if (doA) {
      __builtin_amdgcn_s_setprio(1);
      sA_ = mfma32(ka0_, qfA[0], sA_);
      sA_ = mfma32(ka1_, qfA[1], sA_);
      sA_ = mfma32(ka2_, qfA[2], sA_);
      sA_ = mfma32(ka3_, qfA[3], sA_);
      __builtin_amdgcn_s_setprio(0);
    }

    bf8 pfB0_, pfB1_, pfA0_, pfA1_;
    SOFTMAX32(sB_, t, dtB, qgB, mB, lB, o0B, o1B, pfB0_, pfB1_);
    if (doA) {
      SOFTMAX32(sA_, t, dtA, qgA, mA, lA, o0A, o1A, pfA0_, pfA1_);
    }

    bf8 va0_ = *(const bf8*)(vbuf + ql * 64 + (((hi) ^ prA) << 4));
    bf8 va1_ = *(const bf8*)(vbuf + ql * 64 + (((2 + hi) ^ prA) << 4));
    bf8 vb0_ = *(const bf8*)(vbuf + (32 + ql) * 64 + (((hi) ^ prB) << 4));
    bf8 vb1_ = *(const bf8*)(vbuf + (32 + ql) * 64 + (((2 + hi) ^ prB) << 4));
    SGB();
    asm volatile("s_waitcnt lgkmcnt(0)" ::: "memory");
    SGB();
    if (stage_) STAGE4KV(Vtp, t + 4, vbuf);

    __builtin_amdgcn_s_setprio(1);
    o0B = mfma32(va0_, pfB0_, o0B);
    o0B = mfma32(va1_, pfB1_, o0B);
    o1B = mfma32(vb0_, pfB0_, o1B);
    o1B = mfma32(vb1_, pfB1_, o1B);
    __builtin_amdgcn_s_setprio(0);
    if (doA) {
      __builtin_amdgcn_s_setprio(1);
      o0A = mfma32(va0_, pfA0_, o0A);
      o0A = mfma32(va1_, pfA1_, o0A);
      o1A = mfma32(vb0_, pfA0_, o1A);
      o1A = mfma32(vb1_, pfA1_, o1A);
      __builtin_amdgcn_s_setprio(0);
    }
  }

  __syncthreads();  // all staging consumed; buffers reusable as sO
  MERGE_STORE(qtA, mA, lA, o0A, o1A);
  __syncthreads();  // A's merge reads done before B's writes
  MERGE_STORE(qtB, mB, lB, o0B, o1B);
}

extern "C" void kernel_launch(void* const* d_in, const int* in_sizes, int n_in,
                              void* d_out, int out_size, void* d_ws, size_t ws_size,
                              hipStream_t stream) {
  const float* x  = (const float*)d_in[0];
  const float* Wq = (const float*)d_in[1];
  const float* Wk = (const float*)d_in[2];
  const float* Wv = (const float*)d_in[3];
  const float* Wo = (const float*)d_in[4];
  const float* bo = (const float*)d_in[5];

  unsigned short* xb = (unsigned short*)d_ws;
  unsigned short* wt = xb + (size_t)SEQ * DM;
  unsigned short* Qh = wt + (size_t)4 * DM * DM;
  unsigned short* Kh = Qh + (size_t)SEQ * DM;
  unsigned short* Vt = Kh + (size_t)SEQ * DM;
  unsigned short* cx = Vt + (size_t)SEQ * DM;

  const float qscale = 1.4426950408889634f / 8.0f;  // log2(e)/sqrt(HD)

  // fused prologue: 2304 tw-blocks + 3072 cvt-blocks
  k_pro<<<dim3(2304 + (SEQ * DM) / 1024), 256, 0, stream>>>(
      x, Wq, Wk, Wv, Wo, xb, wt);
  // fused QKV GEMM over Bt=[2304][768] (wt holds Wq^T|Wk^T|Wv^T contiguous)
  k_gemm2<3, 18><<<dim3(SEQ / 128 * 18), 256, 0, stream>>>(
      xb, wt, Qh, Kh, Vt, nullptr, nullptr, qscale);
  k_attn<<<dim3(768), 256, 0, stream>>>(Qh, Kh, Vt, cx);
  k_gemm2<2, 6><<<dim3(SEQ / 128 * 6), 256, 0, stream>>>(
      cx, wt + (size_t)3 * DM * DM, nullptr, nullptr, nullptr,
      (float*)d_out, bo, 1.0f);
}

// Round 23
// 118.235 us; speedup vs baseline: 1.0221x; 1.0221x over previous
//
#include <hip/hip_runtime.h>
#include <stdint.h>

#define SEQ 4096
#define DM 768
#define NH 12
#define HD 64

typedef __attribute__((ext_vector_type(8))) short bf8;
typedef __attribute__((ext_vector_type(4))) float f4;
typedef __attribute__((ext_vector_type(16))) float f32x16;

static __device__ __forceinline__ f4 mfma_bf16(bf8 a, bf8 b, f4 c) {
  return __builtin_amdgcn_mfma_f32_16x16x32_bf16(a, b, c, 0, 0, 0);
}
static __device__ __forceinline__ f32x16 mfma32(bf8 a, bf8 b, f32x16 c) {
  return __builtin_amdgcn_mfma_f32_32x32x16_bf16(a, b, c, 0, 0, 0);
}

// RNE float->bf16 (bit pattern)
static __device__ __forceinline__ unsigned short f2bf(float f) {
  unsigned int u = __float_as_uint(f);
  u += 0x7FFFu + ((u >> 16) & 1u);
  return (unsigned short)(u >> 16);
}

// packed f32 pair -> bf16 pair (lo in low 16, hi in high 16)
static __device__ __forceinline__ unsigned int cvtpk(float lo, float hi) {
  unsigned int r;
  asm("v_cvt_pk_bf16_f32 %0, %1, %2" : "=v"(r) : "v"(lo), "v"(hi));
  return r;
}

static __device__ __forceinline__ void gload_lds16(const void* g, void* l) {
  __builtin_amdgcn_global_load_lds(
      (const __attribute__((address_space(1))) void*)g,
      (__attribute__((address_space(3))) void*)l, 16, 0, 0);
}

// ---- fused prologue: transpose-cast W (blocks 0..2303) + cast x (rest) ----
__global__ __launch_bounds__(256) void k_pro(const float* __restrict__ x,
                                             const float* __restrict__ w0,
                                             const float* __restrict__ w1,
                                             const float* __restrict__ w2,
                                             const float* __restrict__ w3,
                                             unsigned short* __restrict__ xb,
                                             unsigned short* __restrict__ wt) {
  const int id = (int)blockIdx.x;
  if (id < 2304) {
    const int z = id / 576, rem = id % 576;
    const int by = rem / 24, bx = rem % 24;
    const float* W = z == 0 ? w0 : z == 1 ? w1 : z == 2 ? w2 : w3;
    unsigned short* WT = wt + (size_t)z * DM * DM;
    __shared__ float t[32][33];
    int c0 = bx * 32, r0 = by * 32;
    int lx = threadIdx.x & 31, ly = threadIdx.x >> 5;
#pragma unroll
    for (int rr = 0; rr < 32; rr += 8)
      t[ly + rr][lx] = W[(size_t)(r0 + ly + rr) * DM + c0 + lx];
    __syncthreads();
#pragma unroll
    for (int rr = 0; rr < 32; rr += 8)
      WT[(size_t)(c0 + ly + rr) * DM + r0 + lx] = f2bf(t[lx][ly + rr]);
  } else {
    int i = ((id - 2304) * 256 + threadIdx.x) * 4;
    float4 v = *reinterpret_cast<const float4*>(x + i);
    ushort4 o;
    o.x = f2bf(v.x); o.y = f2bf(v.y); o.z = f2bf(v.z); o.w = f2bf(v.w);
    *reinterpret_cast<ushort4*>(xb + i) = o;
  }
}

// ---- bf16 MFMA GEMM, 128x128 tile, 4 waves (2x2), wave tile 64x64 --------
// Single-buffered (R16-proven). 1D grid with XCD-chunked swizzle (T1).
// MODE 3: fused QKV. MODE 2: out-proj.
template <int MODE, int NY>
__global__ __launch_bounds__(256) void k_gemm2(const unsigned short* __restrict__ A,
                                               const unsigned short* __restrict__ Bt,
                                               unsigned short* __restrict__ Qh,
                                               unsigned short* __restrict__ Kh,
                                               unsigned short* __restrict__ Vtl,
                                               float* __restrict__ Cf,
                                               const float* __restrict__ bias,
                                               float qscale) {
  __shared__ unsigned short sA[128 * 32];
  __shared__ unsigned short sB[128 * 32];
  const int t = threadIdx.x, lane = t & 63, w = t >> 6;
  const int wr = w >> 1, wc = w & 1;
  const int c = lane & 15, g = lane >> 4;
  constexpr int NWG = 32 * NY;
  const int L = (int)blockIdx.x;
  const int W = (L & 7) * (NWG / 8) + (L >> 3);
  const int brow = (W / NY) * 128, bcol = (W % NY) * 128;
  f4 acc[4][4] = {};
  for (int k0 = 0; k0 < DM; k0 += 32) {
#pragma unroll
    for (int i = 0; i < 2; ++i) {
      int slot = w * 2 + i;
      int chunk = slot * 64 + lane;
      int row = chunk >> 2;
      int sl = (chunk & 3) ^ ((row >> 1) & 3);
      gload_lds16(A + (size_t)(brow + row) * DM + k0 + sl * 8, &sA[slot * 512]);
    }
#pragma unroll
    for (int i = 0; i < 2; ++i) {
      int slot = w * 2 + i;
      int chunk = slot * 64 + lane;
      int row = chunk >> 2;
      int sl = (chunk & 3) ^ ((row >> 1) & 3);
      gload_lds16(Bt + (size_t)(bcol + row) * DM + k0 + sl * 8, &sB[slot * 512]);
    }
    __syncthreads();
    bf8 af[4], bfr[4];
#pragma unroll
    for (int m = 0; m < 4; ++m) {
      int row = wr * 64 + m * 16 + c;
      int off = row * 64 + ((g * 16) ^ (((row >> 1) & 3) << 4));
      af[m] = *reinterpret_cast<const bf8*>(reinterpret_cast<const char*>(sA) + off);
    }
#pragma unroll
    for (int n = 0; n < 4; ++n) {
      int row = wc * 64 + n * 16 + c;
      int off = row * 64 + ((g * 16) ^ (((row >> 1) & 3) << 4));
      bfr[n] = *reinterpret_cast<const bf8*>(reinterpret_cast<const char*>(sB) + off);
    }
#pragma unroll
    for (int m = 0; m < 4; ++m)
#pragma unroll
      for (int n = 0; n < 4; ++n)
        acc[m][n] = mfma_bf16(af[m], bfr[n], acc[m][n]);
    __syncthreads();
  }
#pragma unroll
  for (int m = 0; m < 4; ++m) {
#pragma unroll
    for (int n = 0; n < 4; ++n) {
      int col = bcol + wc * 64 + n * 16 + c;
      int row0 = brow + wr * 64 + m * 16 + g * 4;
      if (MODE == 3) {
        int zone = col / 768;
        int ci = col - zone * 768;
        int h = ci >> 6, d = ci & 63;
        if (zone == 0) {
#pragma unroll
          for (int r = 0; r < 4; ++r)
            Qh[((size_t)h * SEQ + row0 + r) * 64 + d] = f2bf(acc[m][n][r] * qscale);
        } else if (zone == 1) {
#pragma unroll
          for (int r = 0; r < 4; ++r)
            Kh[((size_t)h * SEQ + row0 + r) * 64 + d] = f2bf(acc[m][n][r]);
        } else {
          ushort4 p;
          p.x = f2bf(acc[m][n][0]); p.y = f2bf(acc[m][n][1]);
          p.z = f2bf(acc[m][n][2]); p.w = f2bf(acc[m][n][3]);
          // row0 = k index; tile = row0>>5, ks = row0&31 (row0%4==0 -> in-tile)
          *reinterpret_cast<ushort4*>(
              Vtl + ((((size_t)h * 128 + (row0 >> 5)) * 64 + d) * 32 + (row0 & 31))) = p;
        }
      } else {
#pragma unroll
        for (int r = 0; r < 4; ++r)
          Cf[(size_t)(row0 + r) * DM + col] = acc[m][n][r] + bias[col];
      }
    }
  }
}

// ---- attention helpers ----------------------------------------------------
#define PSWAP(a, b) asm volatile("v_permlane32_swap_b32 %0, %1" : "+v"(a), "+v"(b))
#define SGB() __builtin_amdgcn_sched_barrier(0)

// Stage a 32x64 bf16 K tile (contiguous 4KB, 128-B rows) into LDS.
// Source pre-swizzled (chunk ^= row&7) to match the swizzled ds_read.
#define STAGE4K(srcbase, tile, dst) do {                                      \
    const unsigned short* s_ = (srcbase) + (size_t)(tile) * 2048 + kLaneOffK; \
    _Pragma("unroll")                                                         \
    for (int j_ = 0; j_ < 4; ++j_)                                            \
      gload_lds16(s_ + j_ * 512, (dst) + j_ * 1024);                          \
  } while (0)

// Stage a 64x32 bf16 V tile (contiguous 4KB, 64-B rows). Source pre-swizzled:
// chunk ^= (row&3)^((row>>2)&3)^((row>>4)&3); row = 16j + (lane>>2).
#define STAGE4KV(srcbase, tile, dst) do {                                     \
    const unsigned short* s_ = (srcbase) + (size_t)(tile) * 2048;             \
    _Pragma("unroll")                                                         \
    for (int j_ = 0; j_ < 4; ++j_) {                                          \
      int c_ = (lane & 3) ^ ((lane >> 2) & 3) ^ ((lane >> 4) & 3) ^ j_;       \
      gload_lds16(s_ + j_ * 512 + (lane >> 2) * 32 + c_ * 8,                  \
                  (dst) + j_ * 1024);                                         \
    }                                                                         \
  } while (0)

// 16 P-values (one f32x16, already masked) -> exp -> two bf8 B-fragments.
#define PBUILD(sv, pfx, pfy) do {                                             \
    float p0_ = __builtin_amdgcn_exp2f(sv[0] - mn_);                          \
    float p1_ = __builtin_amdgcn_exp2f(sv[1] - mn_);                          \
    float p2_ = __builtin_amdgcn_exp2f(sv[2] - mn_);                          \
    float p3_ = __builtin_amdgcn_exp2f(sv[3] - mn_);                          \
    float p4_ = __builtin_amdgcn_exp2f(sv[4] - mn_);                          \
    float p5_ = __builtin_amdgcn_exp2f(sv[5] - mn_);                          \
    float p6_ = __builtin_amdgcn_exp2f(sv[6] - mn_);                          \
    float p7_ = __builtin_amdgcn_exp2f(sv[7] - mn_);                          \
    unsigned int wa0_ = cvtpk(p0_, p1_), wa1_ = cvtpk(p2_, p3_);              \
    unsigned int wb0_ = cvtpk(p4_, p5_), wb1_ = cvtpk(p6_, p7_);              \
    ls_ += ((p0_ + p1_) + (p2_ + p3_)) + ((p4_ + p5_) + (p6_ + p7_));         \
    float q0_ = __builtin_amdgcn_exp2f(sv[8] - mn_);                          \
    float q1_ = __builtin_amdgcn_exp2f(sv[9] - mn_);                          \
    float q2_ = __builtin_amdgcn_exp2f(sv[10] - mn_);                         \
    float q3_ = __builtin_amdgcn_exp2f(sv[11] - mn_);                         \
    float q4_ = __builtin_amdgcn_exp2f(sv[12] - mn_);                         \
    float q5_ = __builtin_amdgcn_exp2f(sv[13] - mn_);                         \
    float q6_ = __builtin_amdgcn_exp2f(sv[14] - mn_);                         \
    float q7_ = __builtin_amdgcn_exp2f(sv[15] - mn_);                         \
    unsigned int wc0_ = cvtpk(q0_, q1_), wc1_ = cvtpk(q2_, q3_);              \
    unsigned int wd0_ = cvtpk(q4_, q5_), wd1_ = cvtpk(q6_, q7_);              \
    ls_ += ((q0_ + q1_) + (q2_ + q3_)) + ((q4_ + q5_) + (q6_ + q7_));         \
    PSWAP(wa0_, wb0_);                                                        \
    PSWAP(wa1_, wb1_);                                                        \
    PSWAP(wc0_, wd0_);                                                        \
    PSWAP(wc1_, wd1_);                                                        \
    uint4 u0_ = {wa0_, wa1_, wb0_, wb1_};                                     \
    uint4 u1_ = {wc0_, wc1_, wd0_, wd1_};                                     \
    pfx = *reinterpret_cast<bf8*>(&u0_);                                      \
    pfy = *reinterpret_cast<bf8*>(&u1_);                                      \
  } while (0)

#define FMAX8(v, i0) fmaxf(fmaxf(fmaxf(v[i0], v[i0+1]), fmaxf(v[i0+2], v[i0+3])), \
                           fmaxf(fmaxf(v[i0+4], v[i0+5]), fmaxf(v[i0+6], v[i0+7])))

// Cross-half (lane i <-> i+32) reduce via permlane32_swap. The opaque asm
// copy forces 'cp' into a register DISTINCT from 'x' (R7 lesson).
#define XHALF_MAX(x) do {                                                     \
    float cp_ = (x);                                                          \
    asm volatile("" : "+v"(cp_));                                             \
    PSWAP((x), cp_);                                                          \
    (x) = fmaxf((x), cp_);                                                    \
  } while (0)
#define XHALF_ADD(x) do {                                                     \
    float cp_ = (x);                                                          \
    asm volatile("" : "+v"(cp_));                                             \
    PSWAP((x), cp_);                                                          \
    (x) = (x) + cp_;                                                          \
  } while (0)

// One KVBLK=32 step. Two-fence form (R19-proven; R20 single-fence merge
// regressed 2x — K and V fragment live ranges must stay disjoint; R22
// paired-sharing also regressed — serial dual softmax).
// Each buffer's ds_reads are SGB/lgkmcnt(0)/SGB-fenced before restage and
// before the consuming MFMAs. Defer-max (T13, THR=8, log2 domain).
#define STEP32(t, stage_) do {                                                \
    asm volatile("s_waitcnt vmcnt(0)" ::: "memory");                          \
    SGB();                                                                    \
    const char* kr0_ = kbuf + ql * 128;                                       \
    bf8 ka0_ = *(const bf8*)(kr0_ + (((hi) ^ xq) << 4));                      \
    bf8 ka1_ = *(const bf8*)(kr0_ + (((2 + hi) ^ xq) << 4));                  \
    bf8 ka2_ = *(const bf8*)(kr0_ + (((4 + hi) ^ xq) << 4));                  \
    bf8 ka3_ = *(const bf8*)(kr0_ + (((6 + hi) ^ xq) << 4));                  \
    SGB();                                                                    \
    asm volatile("s_waitcnt lgkmcnt(0)" ::: "memory");                        \
    SGB();                                                                    \
    if (stage_) STAGE4K(Khp, (t) + 4, kbuf);                                  \
    f32x16 s0_ = {};                                                          \
    __builtin_amdgcn_s_setprio(1);                                            \
    s0_ = mfma32(ka0_, qf[0], s0_);                                           \
    s0_ = mfma32(ka1_, qf[1], s0_);                                           \
    s0_ = mfma32(ka2_, qf[2], s0_);                                           \
    s0_ = mfma32(ka3_, qf[3], s0_);                                           \
    __builtin_amdgcn_s_setprio(0);                                            \
    if ((t) == dt) {                                                          \
      _Pragma("unroll")                                                       \
      for (int r_ = 0; r_ < 16; ++r_) {                                       \
        int kr_ = (t) * 32 + (r_ & 3) + 8 * (r_ >> 2) + 4 * hi;               \
        s0_[r_] = (kr_ > qg) ? -1e30f : s0_[r_];                              \
      }                                                                       \
    }                                                                         \
    float tm_ = fmaxf(FMAX8(s0_, 0), FMAX8(s0_, 8));                          \
    XHALF_MAX(tm_);                                                           \
    float mn_, al_;                                                           \
    if (__all(tm_ <= m + 8.f)) {                                              \
      mn_ = m;                                                                \
      al_ = 1.0f;                                                             \
    } else {                                                                  \
      mn_ = fmaxf(m, tm_);                                                    \
      al_ = __builtin_amdgcn_exp2f(m - mn_);                                  \
      m = mn_;                                                                \
      _Pragma("unroll")                                                       \
      for (int r_ = 0; r_ < 16; ++r_) { o0[r_] *= al_; o1[r_] *= al_; }       \
    }                                                                         \
    float ls_ = 0.f;                                                          \
    bf8 pfA0_, pfA1_;                                                         \
    PBUILD(s0_, pfA0_, pfA1_);                                                \
    XHALF_ADD(ls_);                                                           \
    l = l * al_ + ls_;                                                        \
    bf8 va0_ = *(const bf8*)(vbuf + ql * 64 + (((hi) ^ prA) << 4));           \
    bf8 va1_ = *(const bf8*)(vbuf + ql * 64 + (((2 + hi) ^ prA) << 4));       \
    bf8 vb0_ = *(const bf8*)(vbuf + (32 + ql) * 64 + (((hi) ^ prB) << 4));    \
    bf8 vb1_ = *(const bf8*)(vbuf + (32 + ql) * 64 + (((2 + hi) ^ prB) << 4));\
    SGB();                                                                    \
    asm volatile("s_waitcnt lgkmcnt(0)" ::: "memory");                        \
    SGB();                                                                    \
    if (stage_) STAGE4KV(Vtp, (t) + 4, vbuf);                                 \
    __builtin_amdgcn_s_setprio(1);                                            \
    o0 = mfma32(va0_, pfA0_, o0);                                             \
    o0 = mfma32(va1_, pfA1_, o0);                                             \
    o1 = mfma32(vb0_, pfA0_, o1);                                             \
    o1 = mfma32(vb1_, pfA1_, o1);                                             \
    __builtin_amdgcn_s_setprio(0);                                            \
  } while (0)

// ---- causal flash attention: paired q-tiles + split-K x4 + XCD chunking --
// KVBLK=32 -> 8KB staging/wave -> 33.8KB LDS -> 4 blocks/CU (16 waves).
// K and V LDS-staged from contiguous 4KB tiles, one step ahead, no
// over-staging. sO merge overlays the staging region (pre-merge barrier).
__global__ __launch_bounds__(256, 4) void k_attn(const unsigned short* __restrict__ Qh,
                                                 const unsigned short* __restrict__ Kh,
                                                 const unsigned short* __restrict__ Vt,
                                                 unsigned short* __restrict__ ctx) {
  const int tid = threadIdx.x;
  const int lane = tid & 63;
  const int w = tid >> 6;  // split-K wave index, 0..3
  const int ql = lane & 31, hi = lane >> 5;
  const int xq = ql & 7;
  const int prA = (ql & 3) ^ ((ql >> 2) & 3) ^ ((ql >> 4) & 3);
  const int prB = prA ^ 2;

  const int L = (int)blockIdx.x;          // 0..767
  const int W = (L & 7) * 96 + (L >> 3);  // XCD-chunked work id
  const int h = W >> 6;
  const int b = W & 63;

  __shared__ __align__(16) char smem[33792];
  char* kbuf = smem + w * 4096;           // [0,16K)
  char* vbuf = smem + 16384 + w * 4096;   // [16K,32K)
  float* sO = (float*)smem;               // [4][64][32] overlays staging
  float* sM = (float*)(smem + 32768);     // [4][32]
  float* sL = (float*)(smem + 33280);     // [4][32]

  const unsigned short* Khp = Kh + (size_t)h * SEQ * 64;
  const unsigned short* Qhp = Qh + (size_t)h * SEQ * 64;
  const unsigned short* Vtp = Vt + (size_t)h * SEQ * 64;  // tiled [128][64][32]
  // K staging source offset (shorts): row = lane>>3, chunk^row (128-B rows)
  const int kLaneOffK = (lane >> 3) * 64 + ((lane & 7) ^ (lane >> 3)) * 8;

  for (int ph = 0; ph < 2; ++ph) {
    const int qt = ph ? (127 - b) : b;
    const int qg = qt * 32 + ql;
    const int dt = qt;  // diagonal 32-tile
    bf8 qf[4];
    {
      const unsigned short* qp = Qhp + (size_t)qg * 64 + hi * 8;
      qf[0] = *reinterpret_cast<const bf8*>(qp);
      qf[1] = *reinterpret_cast<const bf8*>(qp + 16);
      qf[2] = *reinterpret_cast<const bf8*>(qp + 32);
      qf[3] = *reinterpret_cast<const bf8*>(qp + 48);
    }
    f32x16 o0 = {}, o1 = {};
    float m = -1e30f, l = 0.f;

    const int nt = (dt >= w) ? ((dt - w) >> 2) + 1 : 0;
    if (nt > 0) {
      STAGE4K(Khp, w, kbuf);
      STAGE4KV(Vtp, w, vbuf);
      for (int i = 0; i < nt; ++i) {
        const int t = w + 4 * i;
        STEP32(t, (i + 1 < nt));
      }
    }
    __syncthreads();  // all staging consumed; buffers reusable as sO

    // ---- 4-way split-K merge via LDS (sO overlays staging region) ----
#pragma unroll
    for (int r = 0; r < 16; ++r) {
      int dr = (r & 3) + 8 * (r >> 2) + 4 * hi;
      sO[w * 2048 + dr * 32 + ql] = o0[r];
      sO[w * 2048 + (32 + dr) * 32 + ql] = o1[r];
    }
    if (hi == 0) { sM[w * 32 + ql] = m; sL[w * 32 + ql] = l; }
    __syncthreads();
    {
      const int q = tid & 31;
      const int dblk = tid >> 5;  // 0..7, 8 d-values each
      float m0 = sM[q], m1 = sM[32 + q], m2 = sM[64 + q], m3 = sM[96 + q];
      float mn = fmaxf(fmaxf(m0, m1), fmaxf(m2, m3));
      float a0 = __builtin_amdgcn_exp2f(m0 - mn);
      float a1 = __builtin_amdgcn_exp2f(m1 - mn);
      float a2 = __builtin_amdgcn_exp2f(m2 - mn);
      float a3 = __builtin_amdgcn_exp2f(m3 - mn);
      float inv = 1.f / (a0 * sL[q] + a1 * sL[32 + q] + a2 * sL[64 + q] + a3 * sL[96 + q]);
      a0 *= inv; a1 *= inv; a2 *= inv; a3 *= inv;
      unsigned short* cp = ctx + (size_t)(qt * 32 + q) * DM + h * HD + dblk * 8;
#pragma unroll
      for (int j = 0; j < 8; j += 2) {
        int d = dblk * 8 + j;
        float v0 = sO[d * 32 + q] * a0 + sO[2048 + d * 32 + q] * a1 +
                   sO[4096 + d * 32 + q] * a2 + sO[6144 + d * 32 + q] * a3;
        float v1 = sO[(d + 1) * 32 + q] * a0 + sO[2048 + (d + 1) * 32 + q] * a1 +
                   sO[4096 + (d + 1) * 32 + q] * a2 + sO[6144 + (d + 1) * 32 + q] * a3;
        *reinterpret_cast<unsigned int*>(cp + j) = cvtpk(v0, v1);
      }
    }
    __syncthreads();  // merge reads done before phase-2 restage
  }
}

extern "C" void kernel_launch(void* const* d_in, const int* in_sizes, int n_in,
                              void* d_out, int out_size, void* d_ws, size_t ws_size,
                              hipStream_t stream) {
  const float* x  = (const float*)d_in[0];
  const float* Wq = (const float*)d_in[1];
  const float* Wk = (const float*)d_in[2];
  const float* Wv = (const float*)d_in[3];
  const float* Wo = (const float*)d_in[4];
  const float* bo = (const float*)d_in[5];

  unsigned short* xb = (unsigned short*)d_ws;
  unsigned short* wt = xb + (size_t)SEQ * DM;
  unsigned short* Qh = wt + (size_t)4 * DM * DM;
  unsigned short* Kh = Qh + (size_t)SEQ * DM;
  unsigned short* Vt = Kh + (size_t)SEQ * DM;
  unsigned short* cx = Vt + (size_t)SEQ * DM;

  const float qscale = 1.4426950408889634f / 8.0f;  // log2(e)/sqrt(HD)

  // fused prologue: 2304 tw-blocks + 3072 cvt-blocks
  k_pro<<<dim3(2304 + (SEQ * DM) / 1024), 256, 0, stream>>>(
      x, Wq, Wk, Wv, Wo, xb, wt);
  // fused QKV GEMM over Bt=[2304][768] (wt holds Wq^T|Wk^T|Wv^T contiguous)
  k_gemm2<3, 18><<<dim3(SEQ / 128 * 18), 256, 0, stream>>>(
      xb, wt, Qh, Kh, Vt, nullptr, nullptr, qscale);
  k_attn<<<dim3(768), 256, 0, stream>>>(Qh, Kh, Vt, cx);
  k_gemm2<2, 6><<<dim3(SEQ / 128 * 6), 256, 0, stream>>>(
      cx, wt + (size_t)3 * DM * DM, nullptr, nullptr, nullptr,
      (float*)d_out, bo, 1.0f);
}